// Round 14
// baseline (182.326 us; speedup 1.0000x reference)
//
#include <hip/hip_runtime.h>
#include <hip/hip_bf16.h>

typedef unsigned int u32;
typedef __attribute__((ext_vector_type(4))) float f32x4;

#define NPAIR 32
#define NCLS  92
#define NCTX  8
#define MAXL  40
#define DIM   768
#define LSUF  31

#define MAT_F4     22609920u     // one matrix in f32x4 units (32*92*40*192)
#define MAT_F4_TOT 45219840u     // both matrices
#define TOTAL_F4   45249280u     // + mask (29440 f32x4)
#define GRID_SWEEP 2048u
#define SWEEP_STRIDE (GRID_SWEEP * 256u)

// ---------------- kernel 1: MLP + attention -> 8 summed rows per (which,pair) ----------------
// 64 blocks = (which, pair); writes sums[which*32+pair][8][768] f32 into d_ws (1.5 MB)
__global__ __launch_bounds__(256) void k_prep(
    const int* __restrict__ so_ids,     // (32,2) int32
    const float* __restrict__ enti,     // (36,256)
    const float* __restrict__ meta,     // (8,768)
    const float* __restrict__ sctx,     // (8,768)
    const float* __restrict__ octx,     // (8,768)
    const float* __restrict__ W1,       // (512,256)
    const float* __restrict__ b1,       // (256)
    const float* __restrict__ W2,       // (256,1536)
    float* __restrict__ sums)           // d_ws: (64,8,768)
{
    const u32 bid = blockIdx.x;
    const u32 t = threadIdx.x;
    const u32 which = bid >> 5;
    const u32 pair = bid & 31u;
    __shared__ float arena[2824];       // so_vec 512 | h 256 | red 2048 | probs 8
    __shared__ int ids[2];

    if (t == 0) {
        bool is64 = true;
        for (int i = 1; i < 64; i += 2) is64 = is64 && (so_ids[i] == 0);
        if (is64) { ids[0] = so_ids[4 * pair]; ids[1] = so_ids[4 * pair + 2]; }
        else      { ids[0] = so_ids[2 * pair]; ids[1] = so_ids[2 * pair + 1]; }
    }
    __syncthreads();

    float* so_vec = arena;            // [0, 512)
    float* h      = arena + 512;      // [512, 768)
    float* red    = arena + 768;      // [768, 2816)
    float* probs  = arena + 2816;     // [2816, 2824)

    so_vec[t]       = enti[ids[0] * 256 + t];
    so_vec[256 + t] = enti[ids[1] * 256 + t];
    __syncthreads();

    {
        float acc = b1[t];
        const float* w = W1 + t;
        #pragma unroll 8
        for (int k = 0; k < 512; ++k)
            acc = fmaf(so_vec[k], w[(size_t)k * 256], acc);
        h[t] = fmaxf(acc, 0.f);
    }
    __syncthreads();

    float qr[3] = {0.f, 0.f, 0.f};
    {
        const float* w = W2 + which * DIM + t;
        #pragma unroll 4
        for (int k = 0; k < 256; ++k) {
            const float hk = h[k];
            #pragma unroll
            for (int i = 0; i < 3; ++i)
                qr[i] = fmaf(hk, w[(size_t)k * 1536 + i * 256], qr[i]);
        }
    }

    #pragma unroll
    for (int c = 0; c < 8; ++c) {
        float pp = 0.f;
        #pragma unroll
        for (int i = 0; i < 3; ++i)
            pp = fmaf(qr[i], meta[c * DIM + t + 256 * i], pp);
        red[c * 256 + t] = pp;
    }
    __syncthreads();
    for (int s = 128; s > 0; s >>= 1) {
        if (t < (u32)s) {
            #pragma unroll
            for (int c = 0; c < 8; ++c)
                red[c * 256 + t] += red[c * 256 + t + s];
        }
        __syncthreads();
    }
    if (t == 0) {
        const float scale = 0.036084391824351615f;  // 1/sqrt(768)
        float sc[8], m = -1e30f;
        #pragma unroll
        for (int c = 0; c < 8; ++c) { sc[c] = red[c * 256] * scale; m = fmaxf(m, sc[c]); }
        float sum = 0.f;
        #pragma unroll
        for (int c = 0; c < 8; ++c) { sc[c] = expf(sc[c] - m); sum += sc[c]; }
        const float inv = 1.f / sum;
        #pragma unroll
        for (int c = 0; c < 8; ++c) probs[c] = sc[c] * inv;
    }
    __syncthreads();

    float pr[8];
    #pragma unroll
    for (int c = 0; c < 8; ++c) pr[c] = probs[c];
    const float* ctxg = which ? octx : sctx;
    float* dst = sums + (size_t)bid * (8u * DIM);
    #pragma unroll
    for (int i = 0; i < 3; ++i) {
        const int d = t + 256 * i;
        float a = 0.f;
        #pragma unroll
        for (int c = 0; c < 8; ++c)
            a = fmaf(pr[c], meta[c * DIM + d], a);
        #pragma unroll
        for (int j = 0; j < 8; ++j)
            dst[j * DIM + d] = ctxg[j * DIM + d] + a;
    }
}

// ---------------- kernel 2: fill-style linear sweep ----------------
// 2048 blocks x 256 thr, no LDS/syncs; iteration i writes the contiguous
// 8 MB window [i*8MB,(i+1)*8MB) -- globally linear store stream like the
// harness fill kernel. Sources come from L2/LLC. NT stores (R10 A/B).
__global__ __launch_bounds__(256) void k_sweep(
    const float* __restrict__ prefix,   // (133,1,768)
    const float* __restrict__ suffix,   // (133,31,768)
    const int* __restrict__ tok_mask,   // (133,40) int32
    const float* __restrict__ sums,     // (64,8,768) in d_ws
    float* __restrict__ out)
{
    const u32 tid0 = blockIdx.x * 256u + threadIdx.x;
    const f32x4* pre4 = (const f32x4*)prefix;
    const f32x4* suf4 = (const f32x4*)suffix;
    const f32x4* sum4 = (const f32x4*)sums;
    f32x4* out4 = (f32x4*)out;

    for (u32 g = tid0; g < TOTAL_F4; g += SWEEP_STRIDE) {
        f32x4 v;
        if (g < MAT_F4_TOT) {
            const u32 which = (g >= MAT_F4) ? 1u : 0u;
            const u32 r = g - which * MAT_F4;
            const u32 row = r / 192u;
            const u32 dpos = r - row * 192u;
            const u32 pair = row / 3680u;          // 92*40
            const u32 rem = row - pair * 3680u;
            const u32 cls = rem / 40u;
            const u32 tok = rem - cls * 40u;
            if (tok == 0u) {
                v = pre4[(cls + 1u) * 192u + dpos];
            } else if (tok < 9u) {
                v = sum4[((which * NPAIR + pair) * 8u + (tok - 1u)) * 192u + dpos];
            } else {
                v = suf4[((cls + 1u) * LSUF + (tok - 9u)) * 192u + dpos];
            }
        } else {
            const u32 m = (g - MAT_F4_TOT) * 4u;
            #pragma unroll
            for (int j = 0; j < 4; ++j) {
                const u32 i = m + (u32)j;
                const u32 rw = i / 40u;
                const u32 tk = i - rw * 40u;
                const u32 cls = rw % 92u;
                v[j] = (float)tok_mask[(cls + 1u) * 40u + tk];
            }
        }
        __builtin_nontemporal_store(v, out4 + g);
    }
}

extern "C" void kernel_launch(void* const* d_in, const int* in_sizes, int n_in,
                              void* d_out, int out_size, void* d_ws, size_t ws_size,
                              hipStream_t stream) {
    const int* so_ids     = (const int*)d_in[0];
    const float* enti     = (const float*)d_in[1];
    const float* prefix   = (const float*)d_in[2];
    const float* suffix   = (const float*)d_in[3];
    const int* tok_mask   = (const int*)d_in[4];
    const float* meta     = (const float*)d_in[5];
    const float* sctx     = (const float*)d_in[6];
    const float* octx     = (const float*)d_in[7];
    const float* W1       = (const float*)d_in[8];
    const float* b1       = (const float*)d_in[9];
    const float* W2       = (const float*)d_in[10];
    float* sums = (float*)d_ws;   // (64,8,768) f32 = 1.5 MB

    k_prep<<<dim3(64), dim3(256), 0, stream>>>(
        so_ids, enti, meta, sctx, octx, W1, b1, W2, sums);
    k_sweep<<<dim3(GRID_SWEEP), dim3(256), 0, stream>>>(
        prefix, suffix, tok_mask, sums, (float*)d_out);
}